// Round 15
// baseline (27.099 us; speedup 1.0000x reference)
//
#include <hip/hip_runtime.h>

// Problem constants (match reference)
constexpr int B = 128, N = 900, C = 91, M = 100;
// ALPHA=0.25, W_CLASS=2 folded analytically:
// ccls = L*(0.5 - s - s^2) - 1.5*s^2*x,  L = log(1+exp(-x)), s = 1/(1+exp(-x))
constexpr float W_GIOU = 2.0f;

constexpr int NBX  = 15;          // blocks in n per batch
constexpr int ROWS = N / NBX;     // 60 rows per block
constexpr int BLK  = 256;
constexpr int MQ   = M / 4;       // 25 output quads per row
constexpr int NGRP = 10;          // row-groups; 250 active threads
constexpr int KIT  = ROWS / NGRP; // 6 iterations per thread (exact)

typedef float f32x4 __attribute__((ext_vector_type(4)));

__global__ __launch_bounds__(BLK) void hungarian_cost_kernel(
    const float* __restrict__ logits,   // [B, N, C]
    const float* __restrict__ pboxes,   // [B, N, 4] cxcywh
    const int*   __restrict__ tlabels,  // [B, M]
    const float* __restrict__ tboxes,   // [B, M, 4] cxcywh
    float* __restrict__ out)            // [B, N, M]
{
    const int b   = blockIdx.y;
    const int n0  = blockIdx.x * ROWS;
    const int tid = threadIdx.x;

    const int mq   = tid % MQ;        // 0..24 (quad of m)
    const int rgrp = tid / MQ;        // 0..10
    if (rgrp >= NGRP) return;         // 6 idle threads; no barriers anywhere

    // Phase stagger: each wave + odd/even block starts its row cycle at a
    // different offset so load bursts / compute / store drains interleave
    // across the CU's resident waves instead of happening in lockstep.
    const int phase0 = (tid >> 6) + ((blockIdx.x & 1) << 1);   // 0..5

    const float*  lbase = logits + ((size_t)b * N + n0) * C;
    const float4* pbp   = reinterpret_cast<const float4*>(pboxes) + (size_t)b * N + n0;
    f32x4*        outq  = reinterpret_cast<f32x4*>(out) + ((size_t)b * N + n0) * MQ;

    // ---- Labels (gather addresses depend on them) ----
    const int4 l4 = reinterpret_cast<const int4*>(tlabels + (size_t)b * M)[mq];
    const int labj[4] = {l4.x, l4.y, l4.z, l4.w};

    // ---- Targets -> registers: xyxy + area only (20 VGPR) ----
    float tx0[4], ty0[4], tx1[4], ty1[4], tar[4];
    {
        const float4* tbp = reinterpret_cast<const float4*>(tboxes) + (size_t)b * M;
        #pragma unroll
        for (int j = 0; j < 4; ++j) {
            const float4 t = tbp[mq * 4 + j];
            tx0[j] = t.x - 0.5f * t.z;  ty0[j] = t.y - 0.5f * t.w;
            tx1[j] = t.x + 0.5f * t.z;  ty1[j] = t.y + 0.5f * t.w;
            tar[j] = (tx1[j] - tx0[j]) * (ty1[j] - ty0[j]);
        }
    }

    // ---- Depth-2 software pipeline with staggered phase ----
    int p = phase0;                      // current phase (row index / NGRP)
    float4 pA, pB;
    float  xA[4], xB[4];
    {
        const int row0 = rgrp + NGRP * p;
        pA = pbp[row0];
        const float* lr = lbase + row0 * C;
        #pragma unroll
        for (int j = 0; j < 4; ++j) xA[j] = lr[labj[j]];
    }

    #pragma unroll
    for (int k = 0; k < KIT; ++k) {
        const int row = rgrp + NGRP * p;
        const int pn  = (p + 1 == KIT) ? 0 : p + 1;

        // ---- Issue next iteration's loads BEFORE computing this one ----
        if (k + 1 < KIT) {
            const int rown = rgrp + NGRP * pn;
            pB = pbp[rown];
            const float* lr = lbase + rown * C;
            #pragma unroll
            for (int j = 0; j < 4; ++j) xB[j] = lr[labj[j]];
        }
        __builtin_amdgcn_sched_barrier(0);   // loads above, compute below

        const float px0 = pA.x - 0.5f * pA.z, py0 = pA.y - 0.5f * pA.w;
        const float px1 = pA.x + 0.5f * pA.z, py1 = pA.y + 0.5f * pA.w;
        const float parea = (px1 - px0) * (py1 - py0);

        f32x4 res;
        #pragma unroll
        for (int j = 0; j < 4; ++j) {
            // focal class cost (ALPHA/W_CLASS folded):
            // e = exp(-x); L = log(1+e); s = rcp(1+e)
            // ccls = L*(0.5 - s - s^2) - 1.5*s^2*x
            const float x    = xA[j];
            const float e    = __expf(-x);
            const float onep = 1.0f + e;
            const float s    = __builtin_amdgcn_rcpf(onep);
            const float L    = __logf(onep);
            const float s2   = s * s;
            const float ccls = L * ((0.5f - s) - s2) - 1.5f * s2 * x;

            // L1 via xyxy deltas: |pc-tc| = 0.5|dx0+dx1|, |pw-tw| = |dx1-dx0|
            const float dx0 = px0 - tx0[j], dx1 = px1 - tx1[j];
            const float dy0 = py0 - ty0[j], dy1 = py1 - ty1[j];
            const float l1a = fabsf(dx0 + dx1) + fabsf(dy0 + dy1);
            const float l1b = fabsf(dx1 - dx0) + fabsf(dy1 - dy0);

            // GIoU, single reciprocal:
            // giou = (inter*earea - uni*(earea-uni)) / (uni*earea)
            const float iw = fmaxf(fminf(px1, tx1[j]) - fmaxf(px0, tx0[j]), 0.0f);
            const float ih = fmaxf(fminf(py1, ty1[j]) - fmaxf(py0, ty0[j]), 0.0f);
            const float inter = iw * ih;
            const float uni   = parea + tar[j] - inter;

            const float ew = fmaxf(px1, tx1[j]) - fminf(px0, tx0[j]);
            const float eh = fmaxf(py1, ty1[j]) - fminf(py0, ty0[j]);
            const float earea = ew * eh;

            const float num  = inter * earea - uni * (earea - uni);
            const float rcpD = __builtin_amdgcn_rcpf(uni * earea);

            res[j] = ccls + 2.5f * l1a + 5.0f * l1b - W_GIOU * (num * rcpD);
        }

        // Non-temporal store: no write-allocate RFO on out lines
        __builtin_nontemporal_store(res, &outq[(size_t)row * MQ + mq]);

        // rotate pipeline regs and advance phase
        pA = pB;
        #pragma unroll
        for (int j = 0; j < 4; ++j) xA[j] = xB[j];
        p = pn;
    }
}

extern "C" void kernel_launch(void* const* d_in, const int* in_sizes, int n_in,
                              void* d_out, int out_size, void* d_ws, size_t ws_size,
                              hipStream_t stream) {
    const float* logits  = (const float*)d_in[0];
    const float* pboxes  = (const float*)d_in[1];
    const int*   tlabels = (const int*)d_in[2];
    const float* tboxes  = (const float*)d_in[3];
    float* out = (float*)d_out;

    dim3 grid(NBX, B);
    dim3 block(BLK);
    hipLaunchKernelGGL(hungarian_cost_kernel, grid, block, 0, stream,
                       logits, pboxes, tlabels, tboxes, out);
}

// Round 16
// 26.617 us; speedup vs baseline: 1.0181x; 1.0181x over previous
//
#include <hip/hip_runtime.h>

// Problem constants (match reference)
constexpr int B = 128, N = 900, C = 91, M = 100;
// ALPHA=0.25, W_CLASS=2 folded analytically:
// ccls = L*(0.5 - s - s^2) - 1.5*s^2*x,  L = log(1+exp(-x)), s = 1/(1+exp(-x))

constexpr int NBX  = 15;          // blocks in n per batch
constexpr int ROWS = N / NBX;     // 60 rows per block
constexpr int BLK  = 256;
constexpr int MQ   = M / 4;       // 25 output quads per row
constexpr int NGRP = 10;          // row-groups; 250 active threads
constexpr int KIT  = ROWS / NGRP; // 6 iterations per thread (exact)

typedef float f32x2 __attribute__((ext_vector_type(2)));
typedef float f32x4 __attribute__((ext_vector_type(4)));

__global__ __launch_bounds__(BLK) void hungarian_cost_kernel(
    const float* __restrict__ logits,   // [B, N, C]
    const float* __restrict__ pboxes,   // [B, N, 4] cxcywh
    const int*   __restrict__ tlabels,  // [B, M]
    const float* __restrict__ tboxes,   // [B, M, 4] cxcywh
    float* __restrict__ out)            // [B, N, M]
{
    const int b   = blockIdx.y;
    const int n0  = blockIdx.x * ROWS;
    const int tid = threadIdx.x;

    const int mq   = tid % MQ;        // 0..24 (quad of m)
    const int rgrp = tid / MQ;        // 0..10
    if (rgrp >= NGRP) return;         // 6 idle threads; no barriers anywhere

    const float*  lbase = logits + ((size_t)b * N + n0) * C;
    const float4* pbp   = reinterpret_cast<const float4*>(pboxes) + (size_t)b * N + n0;
    f32x4*        outq  = reinterpret_cast<f32x4*>(out) + ((size_t)b * N + n0) * MQ;

    // ---- Labels ----
    const int4 l4 = reinterpret_cast<const int4*>(tlabels + (size_t)b * M)[mq];
    const int labj[4] = {l4.x, l4.y, l4.z, l4.w};

    // ---- Targets: packed (x,y) corners + packed (w,h) + area ----
    f32x2 T0[4], T1[4], TWH[4];
    float tar[4];
    {
        const float4* tbp = reinterpret_cast<const float4*>(tboxes) + (size_t)b * M;
        #pragma unroll
        for (int j = 0; j < 4; ++j) {
            const float4 t = tbp[mq * 4 + j];
            const f32x2 c = {t.x, t.y};
            const f32x2 h = {0.5f * t.z, 0.5f * t.w};
            T0[j]  = c - h;                 // pk
            T1[j]  = c + h;                 // pk
            TWH[j] = f32x2{t.z, t.w};
            tar[j] = t.z * t.w;             // area straight from w*h
        }
    }

    // ---- Depth-2 software pipeline: prologue loads for k=0 ----
    float4 pA, pB;
    float  xA[4], xB[4];
    {
        pA = pbp[rgrp];
        const float* lr = lbase + rgrp * C;
        #pragma unroll
        for (int j = 0; j < 4; ++j) xA[j] = lr[labj[j]];
    }

    #pragma unroll
    for (int k = 0; k < KIT; ++k) {
        const int row = rgrp + NGRP * k;

        // ---- Issue k+1's loads BEFORE computing k ----
        if (k + 1 < KIT) {
            const int rown = row + NGRP;
            pB = pbp[rown];
            const float* lr = lbase + rown * C;
            #pragma unroll
            for (int j = 0; j < 4; ++j) xB[j] = lr[labj[j]];
        }
        __builtin_amdgcn_sched_barrier(0);   // loads above, compute below

        // ---- Per-row prep (packed) ----
        const f32x2 Pc  = {pA.x, pA.y};
        const f32x2 Phh = {0.5f * pA.z, 0.5f * pA.w};
        const f32x2 P0  = Pc - Phh;          // pk
        const f32x2 P1  = Pc + Phh;          // pk
        const f32x2 PWH = {pA.z, pA.w};
        const float parea = pA.z * pA.w;     // area from w*h

        f32x4 res;
        #pragma unroll
        for (int j = 0; j < 4; ++j) {
            // ---- focal class cost (ALPHA/W_CLASS folded) ----
            const float x    = xA[j];
            const float e    = __expf(-x);
            const float onep = 1.0f + e;
            const float s    = __builtin_amdgcn_rcpf(onep);
            const float L    = __logf(onep);
            const float s2   = s * s;
            const float ccls = L * ((0.5f - s) - s2) - 1.5f * s2 * x;

            // ---- L1 via packed xyxy deltas ----
            const f32x2 d0 = P0 - T0[j];     // pk
            const f32x2 d1 = P1 - T1[j];     // pk
            const f32x2 sv = d0 + d1;        // pk
            const f32x2 wv = d1 - d0;        // pk
            const float l1a = fabsf(sv.x) + fabsf(sv.y);  // v_add |a|,|b|
            const float l1b = fabsf(wv.x) + fabsf(wv.y);

            // ---- GIoU: min/max only for the intersection corner ----
            const float ix1 = fminf(P1.x, T1[j].x);
            const float iy1 = fminf(P1.y, T1[j].y);
            const float ix0 = fmaxf(P0.x, T0[j].x);
            const float iy0 = fmaxf(P0.y, T0[j].y);
            const f32x2 iwh = f32x2{ix1, iy1} - f32x2{ix0, iy0};   // pk (raw)
            // enclosure via identity: e = (pw+tw) - iw_raw
            const f32x2 ewh = (PWH + TWH[j]) - iwh;                 // 2 pk

            const float iwc = fmaxf(iwh.x, 0.0f);
            const float ihc = fmaxf(iwh.y, 0.0f);
            const float inter = iwc * ihc;
            const float earea = ewh.x * ewh.y;

            const float uni  = (parea + tar[j]) - inter;
            const float t2   = earea - uni;
            const float num  = inter * earea - uni * t2;
            const float rcpD = __builtin_amdgcn_rcpf(uni * earea);

            // res = ccls + 2.5*l1a + 5*l1b - 2*num*rcpD
            res[j] = ccls + 2.5f * l1a + 5.0f * l1b - 2.0f * (num * rcpD);
        }

        // Non-temporal store: no write-allocate RFO on out lines
        __builtin_nontemporal_store(res, &outq[(size_t)row * MQ + mq]);

        // rotate pipeline regs (renames under full unroll)
        pA = pB;
        #pragma unroll
        for (int j = 0; j < 4; ++j) xA[j] = xB[j];
    }
}

extern "C" void kernel_launch(void* const* d_in, const int* in_sizes, int n_in,
                              void* d_out, int out_size, void* d_ws, size_t ws_size,
                              hipStream_t stream) {
    const float* logits  = (const float*)d_in[0];
    const float* pboxes  = (const float*)d_in[1];
    const int*   tlabels = (const int*)d_in[2];
    const float* tboxes  = (const float*)d_in[3];
    float* out = (float*)d_out;

    dim3 grid(NBX, B);
    dim3 block(BLK);
    hipLaunchKernelGGL(hungarian_cost_kernel, grid, block, 0, stream,
                       logits, pboxes, tlabels, tboxes, out);
}